// Round 7
// baseline (305.805 us; speedup 1.0000x reference)
//
#include <hip/hip_runtime.h>
#include <hip/hip_bf16.h>

// HQQ 4-bit linear: out = x @ dequant(W_q)^T + bias
// M=B*S=4096, K=4096, N=4096, GROUP=128. Output FP32.
//
// Round 13: hoisted fragment reads (register double-buffer). Same 256x256 /
// 4-phase/K-tile / 1-barrier-per-phase pipeline as round 12, but each phase
// issues the NEXT phase's ds_read_b128s and MFMAs on registers read LAST
// phase -> LDS latency hides under the 16-MFMA cluster.
//   fragment sets (non-overlapping lifetimes): bv=B kk0, bw=B kk1,
//   ax=A m0-3 (alternating kk), ay=A m4-7 (alternating kk).
//   P1: rd ay(c,k0)       ; st B(T+1,k1); mfma ax*bv (mh0,k0)
//   P2: rd bw,ax(c,k1)    ; st A(T+1,k1); mfma ay*bv (mh1,k0)
//   P3: rd ay(c,k1)       ; st B(T+2,k0); mfma ax*bw (mh0,k1)
//   P4: rd bv,ax(c^1,k0)  ; st A(T+2,k0); mfma ay*bw (mh1,k1)  [vmcnt(2)]
// Safety: every phase begins lgkmcnt(0) BEFORE its barrier -> all waves'
// previous-phase reads complete before any wave's stage lands (WAR); vmcnt(2)
// at P4 (before BAR) retires through A(T+1,kh1) -> tile T+1 fully resident &
// published before its hoisted reads at P4/P2'. Prepass identical to round 12.

typedef __bf16 bf16x8 __attribute__((ext_vector_type(8)));
typedef float f32x4 __attribute__((ext_vector_type(4)));

#define BM 128
#define BN 128
#define BK 64

static __device__ __forceinline__ int pack_bf16x2(float a, float b) {
    __hip_bfloat162 p = __float22bfloat162_rn(make_float2(a, b));
    int r;
    __builtin_memcpy(&r, &p, 4);
    return r;
}

// ---------------- fused pre-pass: convert x AND dequant Wq ------------------
__global__ __launch_bounds__(256) void prepass_kernel(
    const float* __restrict__ X, unsigned short* __restrict__ Ad,
    const int*   __restrict__ Wq,
    const float* __restrict__ scale,
    const float* __restrict__ zero,
    unsigned short* __restrict__ Wd,
    int aUnits, int wUnits, int K, int G, int GROUP)
{
    const int stride = gridDim.x * blockDim.x;
    const int t0     = blockIdx.x * blockDim.x + threadIdx.x;

    for (int u = t0; u < aUnits; u += stride) {
        const long long f = (long long)u * 8;
        const float4 a0 = *(const float4*)(X + f);
        const float4 a1 = *(const float4*)(X + f + 4);
        int4 d;
        d.x = pack_bf16x2(a0.x, a0.y);
        d.y = pack_bf16x2(a0.z, a0.w);
        d.z = pack_bf16x2(a1.x, a1.y);
        d.w = pack_bf16x2(a1.z, a1.w);
        *(int4*)(Ad + f) = d;
    }

    const int unitsPerRow = K >> 3;
    for (int u = t0; u < wUnits; u += stride) {
        const int n = u / unitsPerRow;
        const int k = (u - n * unitsPerRow) * 8;
        const int g = k / GROUP;
        const float s  = scale[(long long)n * G + g];
        const float z  = zero [(long long)n * G + g];
        const float mz = -z * s;

        const long long f = (long long)n * K + k;
        const int4 q0 = *(const int4*)(Wq + f);
        const int4 q1 = *(const int4*)(Wq + f + 4);
        int4 d;
        d.x = pack_bf16x2((float)q0.x * s + mz, (float)q0.y * s + mz);
        d.y = pack_bf16x2((float)q0.z * s + mz, (float)q0.w * s + mz);
        d.z = pack_bf16x2((float)q1.x * s + mz, (float)q1.y * s + mz);
        d.w = pack_bf16x2((float)q1.z * s + mz, (float)q1.w * s + mz);
        *(int4*)(Wd + f) = d;
    }
}

// ---------------- GEMM: 256x256 tile, 4-phase/K-tile, hoisted reads ---------
__global__ __launch_bounds__(512, 2) void gemm256_hoist(
    const unsigned short* __restrict__ A,     // bf16 bits [M,K]
    const unsigned short* __restrict__ Bw,    // bf16 bits [N,K]
    const float* __restrict__ bias,           // fp32 [N]
    float*       __restrict__ C,              // fp32 [M,N]
    int M, int N, int K)
{
    __shared__ unsigned short ldsA[2][2][8192];   // [buf][kh][256x32 packed]
    __shared__ unsigned short ldsB[2][2][8192];

    const int tid  = threadIdx.x;
    const int lane = tid & 63;
    const int wave = tid >> 6;     // 0..7
    const int wm   = wave >> 2;    // 0..1  (M half)
    const int wn   = wave & 3;     // 0..3  (N quarter)

    // XCD-bijective swizzle (nwg % 8 == 0 guaranteed by launcher).
    const int nwg  = (N >> 8) * (M >> 8);
    const int cpx  = nwg >> 3;
    const int bid  = blockIdx.x;
    const int wgid = (bid & 7) * cpx + (bid >> 3);
    const int bx   = wgid % (N >> 8);
    const int by   = wgid / (N >> 8);
    const int blockN0 = bx << 8;
    const int blockM0 = by << 8;

    // staging source offsets per load l (pre-swizzled global; LDS linear)
    long long gSrcA[2], gSrcB[2];
    int ldsDst[2];
#pragma unroll
    for (int l = 0; l < 2; ++l) {
        const int s  = l * 512 + tid;
        const int R  = s >> 3;
        const int j  = s & 7;
        const int ju = j ^ (R & 7);
        const int r  = 2 * R + (ju >> 2);
        const int cc = ju & 3;
        gSrcA[l] = (long long)(blockM0 + r) * K + cc * 8;
        gSrcB[l] = (long long)(blockN0 + r) * K + cc * 8;
        ldsDst[l] = (l * 512 + wave * 64) * 8;   // wave-uniform elem base
    }

    // fragment read offsets (elements within a 16KB subtile)
    const int row16 = lane & 15;
    const int quad  = lane >> 4;
    int offA[8], offB[4];
#pragma unroll
    for (int m = 0; m < 8; ++m) {
        const int r = wm * 128 + m * 16 + row16;
        const int R = r >> 1;
        const int j = (((r & 1) << 2) | quad) ^ (R & 7);
        offA[m] = R * 64 + j * 8;
    }
#pragma unroll
    for (int n = 0; n < 4; ++n) {
        const int r = wn * 64 + n * 16 + row16;
        const int R = r >> 1;
        const int j = (((r & 1) << 2) | quad) ^ (R & 7);
        offB[n] = R * 64 + j * 8;
    }

    f32x4 acc[8][4];
#pragma unroll
    for (int m = 0; m < 8; ++m)
#pragma unroll
        for (int n = 0; n < 4; ++n)
            acc[m][n] = (f32x4){0.f, 0.f, 0.f, 0.f};

#define STAGE_A(T_, KH_)                                                      \
    do {                                                                      \
        const int b_ = (T_) & 1;                                              \
        const long long ko_ = (long long)(T_) * 64 + (KH_) * 32;              \
        __builtin_amdgcn_global_load_lds(                                     \
            (const __attribute__((address_space(1))) unsigned int*)           \
                (A + gSrcA[0] + ko_),                                         \
            (__attribute__((address_space(3))) unsigned int*)                 \
                (&ldsA[b_][KH_][ldsDst[0]]), 16, 0, 0);                       \
        __builtin_amdgcn_global_load_lds(                                     \
            (const __attribute__((address_space(1))) unsigned int*)           \
                (A + gSrcA[1] + ko_),                                         \
            (__attribute__((address_space(3))) unsigned int*)                 \
                (&ldsA[b_][KH_][ldsDst[1]]), 16, 0, 0);                       \
    } while (0)

#define STAGE_B(T_, KH_)                                                      \
    do {                                                                      \
        const int b_ = (T_) & 1;                                              \
        const long long ko_ = (long long)(T_) * 64 + (KH_) * 32;              \
        __builtin_amdgcn_global_load_lds(                                     \
            (const __attribute__((address_space(1))) unsigned int*)           \
                (Bw + gSrcB[0] + ko_),                                        \
            (__attribute__((address_space(3))) unsigned int*)                 \
                (&ldsB[b_][KH_][ldsDst[0]]), 16, 0, 0);                       \
        __builtin_amdgcn_global_load_lds(                                     \
            (const __attribute__((address_space(1))) unsigned int*)           \
                (Bw + gSrcB[1] + ko_),                                        \
            (__attribute__((address_space(3))) unsigned int*)                 \
                (&ldsB[b_][KH_][ldsDst[1]]), 16, 0, 0);                       \
    } while (0)

// hoisted fragment reads into persistent named registers
#define READ_BV(c_)                                                           \
    bv0 = *(const bf16x8*)&ldsB[c_][0][offB[0]];                              \
    bv1 = *(const bf16x8*)&ldsB[c_][0][offB[1]];                              \
    bv2 = *(const bf16x8*)&ldsB[c_][0][offB[2]];                              \
    bv3 = *(const bf16x8*)&ldsB[c_][0][offB[3]];

#define READ_BW(c_)                                                           \
    bw0 = *(const bf16x8*)&ldsB[c_][1][offB[0]];                              \
    bw1 = *(const bf16x8*)&ldsB[c_][1][offB[1]];                              \
    bw2 = *(const bf16x8*)&ldsB[c_][1][offB[2]];                              \
    bw3 = *(const bf16x8*)&ldsB[c_][1][offB[3]];

#define READ_AX(c_, kh_)                                                      \
    ax0 = *(const bf16x8*)&ldsA[c_][kh_][offA[0]];                            \
    ax1 = *(const bf16x8*)&ldsA[c_][kh_][offA[1]];                            \
    ax2 = *(const bf16x8*)&ldsA[c_][kh_][offA[2]];                            \
    ax3 = *(const bf16x8*)&ldsA[c_][kh_][offA[3]];

#define READ_AY(c_, kh_)                                                      \
    ay0 = *(const bf16x8*)&ldsA[c_][kh_][offA[4]];                            \
    ay1 = *(const bf16x8*)&ldsA[c_][kh_][offA[5]];                            \
    ay2 = *(const bf16x8*)&ldsA[c_][kh_][offA[6]];                            \
    ay3 = *(const bf16x8*)&ldsA[c_][kh_][offA[7]];

#define MFROW4(mi_, av_, b0_, b1_, b2_, b3_)                                  \
    acc[mi_][0] = __builtin_amdgcn_mfma_f32_16x16x32_bf16(av_, b0_, acc[mi_][0], 0, 0, 0); \
    acc[mi_][1] = __builtin_amdgcn_mfma_f32_16x16x32_bf16(av_, b1_, acc[mi_][1], 0, 0, 0); \
    acc[mi_][2] = __builtin_amdgcn_mfma_f32_16x16x32_bf16(av_, b2_, acc[mi_][2], 0, 0, 0); \
    acc[mi_][3] = __builtin_amdgcn_mfma_f32_16x16x32_bf16(av_, b3_, acc[mi_][3], 0, 0, 0);

#define MF16_X(b0_, b1_, b2_, b3_)   /* rows 0-3 with ax */                   \
    __builtin_amdgcn_s_setprio(1);                                            \
    MFROW4(0, ax0, b0_, b1_, b2_, b3_);                                       \
    MFROW4(1, ax1, b0_, b1_, b2_, b3_);                                       \
    MFROW4(2, ax2, b0_, b1_, b2_, b3_);                                       \
    MFROW4(3, ax3, b0_, b1_, b2_, b3_);                                       \
    __builtin_amdgcn_s_setprio(0);

#define MF16_Y(b0_, b1_, b2_, b3_)   /* rows 4-7 with ay */                   \
    __builtin_amdgcn_s_setprio(1);                                            \
    MFROW4(4, ay0, b0_, b1_, b2_, b3_);                                       \
    MFROW4(5, ay1, b0_, b1_, b2_, b3_);                                       \
    MFROW4(6, ay2, b0_, b1_, b2_, b3_);                                       \
    MFROW4(7, ay3, b0_, b1_, b2_, b3_);                                       \
    __builtin_amdgcn_s_setprio(0);

#define LGKM0() asm volatile("s_waitcnt lgkmcnt(0)" ::: "memory")
#define BAR()   __builtin_amdgcn_s_barrier()

    const int NT = K >> 6;   // K-tiles of 64; NT=64 here

    // ---- prologue: tile0 full + tile1 kh0 staged; hoisted reads for P1(0) --
    STAGE_A(0, 0); STAGE_B(0, 0); STAGE_A(0, 1); STAGE_B(0, 1);
    STAGE_B(1, 0); STAGE_A(1, 0);
    asm volatile("s_waitcnt vmcnt(4)" ::: "memory");   // tile0 resident
    BAR();

    bf16x8 bv0, bv1, bv2, bv3, bw0, bw1, bw2, bw3;
    bf16x8 ax0, ax1, ax2, ax3, ay0, ay1, ay2, ay3;

    READ_BV(0);
    READ_AX(0, 0);

    // ---- main loop ----
#pragma unroll 2
    for (int T = 0; T <= NT - 3; ++T) {
        const int c = T & 1, cn = c ^ 1;
        // P1: rd ay(c,k0); st B(T+1,k1); mfma ax*bv
        LGKM0(); BAR();
        STAGE_B(T + 1, 1);
        READ_AY(c, 0);
        MF16_X(bv0, bv1, bv2, bv3);
        // P2: rd bw,ax(c,k1); st A(T+1,k1); mfma ay*bv
        LGKM0(); BAR();
        STAGE_A(T + 1, 1);
        READ_BW(c);
        READ_AX(c, 1);
        MF16_Y(bv0, bv1, bv2, bv3);
        // P3: rd ay(c,k1); st B(T+2,k0); mfma ax*bw
        LGKM0(); BAR();
        STAGE_B(T + 2, 0);
        READ_AY(c, 1);
        MF16_X(bw0, bw1, bw2, bw3);
        // P4: rd bv,ax(cn,k0); st A(T+2,k0); mfma ay*bw
        LGKM0();
        asm volatile("s_waitcnt vmcnt(2)" ::: "memory");  // T+1 fully resident
        BAR();
        STAGE_A(T + 2, 0);
        READ_BV(cn);
        READ_AX(cn, 0);
        MF16_Y(bw0, bw1, bw2, bw3);
    }

    // ---- epilogue: tile NT-2 (stage tile NT-1 kh1), then tile NT-1 ----
    {
        const int cE = (NT - 2) & 1, cL = (NT - 1) & 1;
        // eP1
        LGKM0(); BAR();
        STAGE_B(NT - 1, 1);
        READ_AY(cE, 0);
        MF16_X(bv0, bv1, bv2, bv3);
        // eP2
        LGKM0(); BAR();
        STAGE_A(NT - 1, 1);
        READ_BW(cE);
        READ_AX(cE, 1);
        MF16_Y(bv0, bv1, bv2, bv3);
        // eP3 (no stage -> no barrier needed)
        READ_AY(cE, 1);
        MF16_X(bw0, bw1, bw2, bw3);
        // eP4: drain all stages, publish, then hoisted reads of tile NT-1
        asm volatile("s_waitcnt vmcnt(0)" ::: "memory");
        BAR();
        READ_BV(cL);
        READ_AX(cL, 0);
        MF16_Y(bw0, bw1, bw2, bw3);
        // tile NT-1: fully resident & published; no writers -> no barriers
        READ_AY(cL, 0);
        MF16_X(bv0, bv1, bv2, bv3);
        READ_BW(cL);
        READ_AX(cL, 1);
        MF16_Y(bv0, bv1, bv2, bv3);
        READ_AY(cL, 1);
        MF16_X(bw0, bw1, bw2, bw3);
        MF16_Y(bw0, bw1, bw2, bw3);
    }

#undef STAGE_A
#undef STAGE_B
#undef READ_BV
#undef READ_BW
#undef READ_AX
#undef READ_AY
#undef MFROW4
#undef MF16_X
#undef MF16_Y
#undef LGKM0
#undef BAR

    // ---- C write: layout col=lane&15, row=quad*4+reg [m89-verified] ----
    const int colBase = blockN0 + wn * 64;
    const int rowBase = blockM0 + wm * 128;
    float biasf[4];
#pragma unroll
    for (int n = 0; n < 4; ++n)
        biasf[n] = bias[colBase + n * 16 + row16];

#pragma unroll
    for (int m = 0; m < 8; ++m) {
        const int row0 = rowBase + m * 16 + quad * 4;
#pragma unroll
        for (int n = 0; n < 4; ++n) {
            const int col = colBase + n * 16 + row16;
#pragma unroll
            for (int r = 0; r < 4; ++r) {
                C[(long long)(row0 + r) * N + col] = acc[m][n][r] + biasf[n];
            }
        }
    }
}

// ---------------- legacy 128x128 GEMM (fallback for odd shapes) -------------
__global__ __launch_bounds__(256, 2) void gemm_bf16_nt(
    const unsigned short* __restrict__ A,
    const unsigned short* __restrict__ Bw,
    const float* __restrict__ bias,
    float*       __restrict__ C,
    int M, int N, int K)
{
    __shared__ unsigned short ldsA[BM * BK];
    __shared__ unsigned short ldsB[BN * BK];

    const int tid   = threadIdx.x;
    const int lane  = tid & 63;
    const int wave  = tid >> 6;
    const int waveM = wave >> 1;
    const int waveN = wave & 1;

    const int blockN0 = blockIdx.x * BN;
    const int blockM0 = blockIdx.y * BM;

    const long long aBase = (long long)blockM0 * K;
    const long long bBase = (long long)blockN0 * K;

    const int rowInChunk = lane >> 3;
    const int colChunkSw = (lane & 7) ^ rowInChunk;
    const int col8       = colChunkSw * 8;

    f32x4 acc[4][4];
#pragma unroll
    for (int i = 0; i < 4; ++i)
#pragma unroll
        for (int j = 0; j < 4; ++j)
            acc[i][j] = (f32x4){0.f, 0.f, 0.f, 0.f};

    const int row16 = lane & 15;
    const int quad  = lane >> 4;
    const int sw    = row16 & 7;

    for (int k0 = 0; k0 < K; k0 += BK) {
        __syncthreads();
#pragma unroll
        for (int c = 0; c < 4; ++c) {
            const int chunk = (wave << 2) | c;
            const int row   = (chunk << 3) | rowInChunk;
            const unsigned short* gA = A  + aBase + (long long)row * K + k0 + col8;
            const unsigned short* gB = Bw + bBase + (long long)row * K + k0 + col8;
            __builtin_amdgcn_global_load_lds(
                (const __attribute__((address_space(1))) unsigned int*)gA,
                (__attribute__((address_space(3))) unsigned int*)&ldsA[chunk * 512],
                16, 0, 0);
            __builtin_amdgcn_global_load_lds(
                (const __attribute__((address_space(1))) unsigned int*)gB,
                (__attribute__((address_space(3))) unsigned int*)&ldsB[chunk * 512],
                16, 0, 0);
        }
        __syncthreads();

#pragma unroll
        for (int kk = 0; kk < 2; ++kk) {
            bf16x8 av[4], bv[4];
#pragma unroll
            for (int i = 0; i < 4; ++i) {
                const int r    = waveM * 64 + i * 16 + row16;
                const int slot = (kk * 4 + quad) ^ sw;
                av[i] = *(const bf16x8*)&ldsA[r * BK + slot * 8];
            }
#pragma unroll
            for (int j = 0; j < 4; ++j) {
                const int r    = waveN * 64 + j * 16 + row16;
                const int slot = (kk * 4 + quad) ^ sw;
                bv[j] = *(const bf16x8*)&ldsB[r * BK + slot * 8];
            }
#pragma unroll
            for (int i = 0; i < 4; ++i)
#pragma unroll
                for (int j = 0; j < 4; ++j)
                    acc[i][j] = __builtin_amdgcn_mfma_f32_16x16x32_bf16(
                        av[i], bv[j], acc[i][j], 0, 0, 0);
        }
    }

    const int colBase = blockN0 + waveN * 64;
    const int rowBase = blockM0 + waveM * 64;
    float biasf[4];
#pragma unroll
    for (int j = 0; j < 4; ++j)
        biasf[j] = bias[colBase + j * 16 + row16];

#pragma unroll
    for (int i = 0; i < 4; ++i) {
        const int row0 = rowBase + i * 16 + quad * 4;
#pragma unroll
        for (int j = 0; j < 4; ++j) {
            const int col = colBase + j * 16 + row16;
#pragma unroll
            for (int r = 0; r < 4; ++r) {
                C[(long long)(row0 + r) * N + col] = acc[i][j][r] + biasf[j];
            }
        }
    }
}

// ---------------- fallback: fused kernel (no workspace) ---------------------
__global__ __launch_bounds__(256) void hqq_gemm_fused_f32(
    const float* __restrict__ A,
    const int*   __restrict__ Wq,
    const float* __restrict__ scale,
    const float* __restrict__ zero,
    const float* __restrict__ bias,
    float*       __restrict__ C,
    int M, int N, int K, int G, int GROUP)
{
    __shared__ unsigned short ldsA[BM * BK];
    __shared__ unsigned short ldsB[BN * BK];

    const int tid   = threadIdx.x;
    const int lane  = tid & 63;
    const int wave  = tid >> 6;
    const int waveM = wave >> 1;
    const int waveN = wave & 1;

    const int blockN0 = blockIdx.x * BN;
    const int blockM0 = blockIdx.y * BM;

    const int row16 = lane & 15;
    const int quad  = lane >> 4;

    f32x4 acc[4][4];
#pragma unroll
    for (int i = 0; i < 4; ++i)
#pragma unroll
        for (int j = 0; j < 4; ++j)
            acc[i][j] = (f32x4){0.f, 0.f, 0.f, 0.f};

    for (int k0 = 0; k0 < K; k0 += BK) {
        const int g = k0 / GROUP;
        int4 ra[4], rb[4];
#pragma unroll
        for (int c = 0; c < 4; ++c) {
            const int chunk = c * 256 + tid;
            const int row   = chunk >> 3;
            const int col   = (chunk & 7) * 8;

            const float* ap = A + (long long)(blockM0 + row) * K + k0 + col;
            const float4 a0 = *(const float4*)(ap);
            const float4 a1 = *(const float4*)(ap + 4);
            int4 da;
            da.x = pack_bf16x2(a0.x, a0.y);
            da.y = pack_bf16x2(a0.z, a0.w);
            da.z = pack_bf16x2(a1.x, a1.y);
            da.w = pack_bf16x2(a1.z, a1.w);
            ra[c] = da;

            const int n = blockN0 + row;
            const float s  = scale[(long long)n * G + g];
            const float z  = zero [(long long)n * G + g];
            const float mz = -z * s;
            const long long wb = (long long)n * K + k0 + col;
            const int4 q0 = *(const int4*)(Wq + wb);
            const int4 q1 = *(const int4*)(Wq + wb + 4);
            int4 db;
            db.x = pack_bf16x2((float)q0.x * s + mz, (float)q0.y * s + mz);
            db.y = pack_bf16x2((float)q0.z * s + mz, (float)q0.w * s + mz);
            db.z = pack_bf16x2((float)q1.x * s + mz, (float)q1.y * s + mz);
            db.w = pack_bf16x2((float)q1.z * s + mz, (float)q1.w * s + mz);
            rb[c] = db;
        }

        __syncthreads();
#pragma unroll
        for (int c = 0; c < 4; ++c) {
            const int chunk = c * 256 + tid;
            *(int4*)&ldsA[chunk * 8] = ra[c];
            *(int4*)&ldsB[chunk * 8] = rb[c];
        }
        __syncthreads();

#pragma unroll
        for (int kk = 0; kk < 2; ++kk) {
            const int kOff = kk * 32 + quad * 8;
            bf16x8 av[4], bv[4];
#pragma unroll
            for (int i = 0; i < 4; ++i)
                av[i] = *(const bf16x8*)&ldsA[(waveM * 64 + i * 16 + row16) * BK + kOff];
#pragma unroll
            for (int j = 0; j < 4; ++j)
                bv[j] = *(const bf16x8*)&ldsB[(waveN * 64 + j * 16 + row16) * BK + kOff];
#pragma unroll
            for (int i = 0; i < 4; ++i)
#pragma unroll
                for (int j = 0; j < 4; ++j)
                    acc[i][j] = __builtin_amdgcn_mfma_f32_16x16x32_bf16(
                        av[i], bv[j], acc[i][j], 0, 0, 0);
        }
    }

    const int colBase = blockN0 + waveN * 64;
    const int rowBase = blockM0 + waveM * 64;
    float biasf[4];
#pragma unroll
    for (int j = 0; j < 4; ++j)
        biasf[j] = bias[colBase + j * 16 + row16];

#pragma unroll
    for (int i = 0; i < 4; ++i) {
        const int row0 = rowBase + i * 16 + quad * 4;
#pragma unroll
        for (int j = 0; j < 4; ++j) {
            const int col = colBase + j * 16 + row16;
#pragma unroll
            for (int r = 0; r < 4; ++r) {
                C[(long long)(row0 + r) * N + col] = acc[i][j][r] + biasf[j];
            }
        }
    }
}

extern "C" void kernel_launch(void* const* d_in, const int* in_sizes, int n_in,
                              void* d_out, int out_size, void* d_ws, size_t ws_size,
                              hipStream_t stream) {
    (void)n_in; (void)out_size;

    const float* x     = (const float*)d_in[0];
    const int*   Wq    = (const int*)d_in[1];
    const float* scale = (const float*)d_in[2];
    const float* zero  = (const float*)d_in[3];
    const float* bias  = (const float*)d_in[4];
    float*       out   = (float*)d_out;

    const int N     = in_sizes[4];            // 4096
    const int G     = in_sizes[2] / N;        // 32
    const int K     = in_sizes[1] / N;        // 4096
    const int M     = in_sizes[0] / K;        // 4096 (B*S)
    const int GROUP = K / G;                  // 128

    const size_t needWs = (size_t)N * K * 2 + (size_t)M * K * 2;  // 64 MB

    if (ws_size >= needWs) {
        unsigned short* Wd = (unsigned short*)d_ws;                        // [N,K] bf16
        unsigned short* Ad = (unsigned short*)((char*)d_ws + (size_t)N * K * 2);  // [M,K] bf16

        const int aUnits = (int)((long long)M * K / 8);
        const int wUnits = (int)((long long)N * K / 8);
        prepass_kernel<<<2048, 256, 0, stream>>>(x, Ad, Wq, scale, zero, Wd,
                                                 aUnits, wUnits, K, G, GROUP);

        const int nwg = (N >> 8) * (M >> 8);
        const int NT  = K >> 6;
        if ((M % 256) == 0 && (N % 256) == 0 && (K % 64) == 0 && NT >= 4 &&
            (nwg % 8) == 0) {
            gemm256_hoist<<<nwg, 512, 0, stream>>>(Ad, Wd, bias, out, M, N, K);
        } else {
            dim3 grid(N / BN, M / BM);
            gemm_bf16_nt<<<grid, 256, 0, stream>>>(Ad, Wd, bias, out, M, N, K);
        }
    } else {
        dim3 grid(N / BN, M / BM);
        hqq_gemm_fused_f32<<<grid, 256, 0, stream>>>(x, Wq, scale, zero, bias, out,
                                                     M, N, K, G, GROUP);
    }
}

// Round 8
// 285.883 us; speedup vs baseline: 1.0697x; 1.0697x over previous
//
#include <hip/hip_runtime.h>
#include <hip/hip_bf16.h>

// HQQ 4-bit linear: out = x @ dequant(W_q)^T + bias
// M=B*S=4096, K=4096, N=4096, GROUP=128. Output FP32.
//
// Round 14: GEMM reverted byte-identical to round 12 (256x256, 4-phase/K-tile,
// 1 barrier/phase, race-free stage mapping, vmcnt(4)/tile -- 121us, MfmaUtil
// 52%, twice-reproduced). Round 13's hoisted-read variant regressed (145us):
// lgkmcnt(0)-before-barrier made all waves sync on the slowest LDS drain,
// defeating the compiler's fine-grained lgkmcnt interleave.
// Prepass rewritten for MLP: A-convert + W-dequant fused in ONE loop body
// (96B of independent loads in flight/thread/iter), and the runtime division
// u/(K/8) replaced by shifts (K/8, GROUP/8 are pow2 -- launcher-checked).

typedef __bf16 bf16x8 __attribute__((ext_vector_type(8)));
typedef float f32x4 __attribute__((ext_vector_type(4)));

#define BM 128
#define BN 128
#define BK 64

static __device__ __forceinline__ int pack_bf16x2(float a, float b) {
    __hip_bfloat162 p = __float22bfloat162_rn(make_float2(a, b));
    int r;
    __builtin_memcpy(&r, &p, 4);
    return r;
}

// ---------------- pre-pass: fused x->bf16 + Wq dequant, shift indexing ------
__global__ __launch_bounds__(256) void prepass_kernel(
    const float* __restrict__ X, unsigned short* __restrict__ Ad,
    const int*   __restrict__ Wq,
    const float* __restrict__ scale,
    const float* __restrict__ zero,
    unsigned short* __restrict__ Wd,
    int aUnits, int wUnits, int G,
    int rowShift,    // log2(K/8)   : unit -> row n
    int grpShift)    // log2(GROUP/8): unit-in-row -> group g
{
    const int stride  = gridDim.x * blockDim.x;
    const int t0      = blockIdx.x * blockDim.x + threadIdx.x;
    const int rowMask = (1 << rowShift) - 1;

    const int common = (aUnits < wUnits) ? aUnits : wUnits;

    for (int u = t0; u < common; u += stride) {
        const long long f = (long long)u * 8;
        // ---- issue all independent loads first (MLP) ----
        const float4 a0 = *(const float4*)(X + f);
        const float4 a1 = *(const float4*)(X + f + 4);
        const int4   q0 = *(const int4*)(Wq + f);
        const int4   q1 = *(const int4*)(Wq + f + 4);
        const int n = u >> rowShift;
        const int g = (u & rowMask) >> grpShift;
        const float s = scale[(long long)n * G + g];
        const float z = zero [(long long)n * G + g];

        // ---- A: fp32 -> bf16 ----
        int4 da;
        da.x = pack_bf16x2(a0.x, a0.y);
        da.y = pack_bf16x2(a0.z, a0.w);
        da.z = pack_bf16x2(a1.x, a1.y);
        da.w = pack_bf16x2(a1.z, a1.w);
        *(int4*)(Ad + f) = da;

        // ---- W: dequant -> bf16 ----
        const float mz = -z * s;
        int4 dw;
        dw.x = pack_bf16x2((float)q0.x * s + mz, (float)q0.y * s + mz);
        dw.y = pack_bf16x2((float)q0.z * s + mz, (float)q0.w * s + mz);
        dw.z = pack_bf16x2((float)q1.x * s + mz, (float)q1.y * s + mz);
        dw.w = pack_bf16x2((float)q1.z * s + mz, (float)q1.w * s + mz);
        *(int4*)(Wd + f) = dw;
    }

    // tails (empty when M == N)
    for (int u = common + t0; u < aUnits; u += stride) {
        const long long f = (long long)u * 8;
        const float4 a0 = *(const float4*)(X + f);
        const float4 a1 = *(const float4*)(X + f + 4);
        int4 da;
        da.x = pack_bf16x2(a0.x, a0.y);
        da.y = pack_bf16x2(a0.z, a0.w);
        da.z = pack_bf16x2(a1.x, a1.y);
        da.w = pack_bf16x2(a1.z, a1.w);
        *(int4*)(Ad + f) = da;
    }
    for (int u = common + t0; u < wUnits; u += stride) {
        const long long f = (long long)u * 8;
        const int4 q0 = *(const int4*)(Wq + f);
        const int4 q1 = *(const int4*)(Wq + f + 4);
        const int n = u >> rowShift;
        const int g = (u & rowMask) >> grpShift;
        const float s = scale[(long long)n * G + g];
        const float z = zero [(long long)n * G + g];
        const float mz = -z * s;
        int4 dw;
        dw.x = pack_bf16x2((float)q0.x * s + mz, (float)q0.y * s + mz);
        dw.y = pack_bf16x2((float)q0.z * s + mz, (float)q0.w * s + mz);
        dw.z = pack_bf16x2((float)q1.x * s + mz, (float)q1.y * s + mz);
        dw.w = pack_bf16x2((float)q1.z * s + mz, (float)q1.w * s + mz);
        *(int4*)(Wd + f) = dw;
    }
}

// ---------------- GEMM: 256x256 tile, 4-phase/K-tile, 1 barrier/phase -------
// Byte-identical to round 12 (121us, MfmaUtil 52%, race-free).
__global__ __launch_bounds__(512, 2) void gemm256_8ph(
    const unsigned short* __restrict__ A,     // bf16 bits [M,K]
    const unsigned short* __restrict__ Bw,    // bf16 bits [N,K]
    const float* __restrict__ bias,           // fp32 [N]
    float*       __restrict__ C,              // fp32 [M,N]
    int M, int N, int K)
{
    __shared__ unsigned short ldsA[2][2][8192];   // [buf][kh][256x32 packed]
    __shared__ unsigned short ldsB[2][2][8192];

    const int tid  = threadIdx.x;
    const int lane = tid & 63;
    const int wave = tid >> 6;     // 0..7
    const int wm   = wave >> 2;    // 0..1  (M half)
    const int wn   = wave & 3;     // 0..3  (N quarter)

    // XCD-bijective swizzle (nwg % 8 == 0 guaranteed by launcher).
    const int nwg  = (N >> 8) * (M >> 8);
    const int cpx  = nwg >> 3;
    const int bid  = blockIdx.x;
    const int wgid = (bid & 7) * cpx + (bid >> 3);
    const int bx   = wgid % (N >> 8);
    const int by   = wgid / (N >> 8);
    const int blockN0 = bx << 8;
    const int blockM0 = by << 8;

    // staging source offsets per load l (pre-swizzled global; LDS linear)
    long long gSrcA[2], gSrcB[2];
    int ldsDst[2];
#pragma unroll
    for (int l = 0; l < 2; ++l) {
        const int s  = l * 512 + tid;
        const int R  = s >> 3;
        const int j  = s & 7;
        const int ju = j ^ (R & 7);
        const int r  = 2 * R + (ju >> 2);
        const int cc = ju & 3;
        gSrcA[l] = (long long)(blockM0 + r) * K + cc * 8;
        gSrcB[l] = (long long)(blockN0 + r) * K + cc * 8;
        ldsDst[l] = (l * 512 + wave * 64) * 8;   // wave-uniform elem base
    }

    // fragment read offsets (elements within a 16KB subtile)
    const int row16 = lane & 15;
    const int quad  = lane >> 4;
    int offA[8], offB[4];
#pragma unroll
    for (int m = 0; m < 8; ++m) {
        const int r = wm * 128 + m * 16 + row16;
        const int R = r >> 1;
        const int j = (((r & 1) << 2) | quad) ^ (R & 7);
        offA[m] = R * 64 + j * 8;
    }
#pragma unroll
    for (int n = 0; n < 4; ++n) {
        const int r = wn * 64 + n * 16 + row16;
        const int R = r >> 1;
        const int j = (((r & 1) << 2) | quad) ^ (R & 7);
        offB[n] = R * 64 + j * 8;
    }

    f32x4 acc[8][4];
#pragma unroll
    for (int m = 0; m < 8; ++m)
#pragma unroll
        for (int n = 0; n < 4; ++n)
            acc[m][n] = (f32x4){0.f, 0.f, 0.f, 0.f};

#define STAGE_A(T_, KH_)                                                      \
    do {                                                                      \
        const int b_ = (T_) & 1;                                              \
        const long long ko_ = (long long)(T_) * 64 + (KH_) * 32;              \
        __builtin_amdgcn_global_load_lds(                                     \
            (const __attribute__((address_space(1))) unsigned int*)           \
                (A + gSrcA[0] + ko_),                                         \
            (__attribute__((address_space(3))) unsigned int*)                 \
                (&ldsA[b_][KH_][ldsDst[0]]), 16, 0, 0);                       \
        __builtin_amdgcn_global_load_lds(                                     \
            (const __attribute__((address_space(1))) unsigned int*)           \
                (A + gSrcA[1] + ko_),                                         \
            (__attribute__((address_space(3))) unsigned int*)                 \
                (&ldsA[b_][KH_][ldsDst[1]]), 16, 0, 0);                       \
    } while (0)

#define STAGE_B(T_, KH_)                                                      \
    do {                                                                      \
        const int b_ = (T_) & 1;                                              \
        const long long ko_ = (long long)(T_) * 64 + (KH_) * 32;              \
        __builtin_amdgcn_global_load_lds(                                     \
            (const __attribute__((address_space(1))) unsigned int*)           \
                (Bw + gSrcB[0] + ko_),                                        \
            (__attribute__((address_space(3))) unsigned int*)                 \
                (&ldsB[b_][KH_][ldsDst[0]]), 16, 0, 0);                       \
        __builtin_amdgcn_global_load_lds(                                     \
            (const __attribute__((address_space(1))) unsigned int*)           \
                (Bw + gSrcB[1] + ko_),                                        \
            (__attribute__((address_space(3))) unsigned int*)                 \
                (&ldsB[b_][KH_][ldsDst[1]]), 16, 0, 0);                       \
    } while (0)

#define READ_BV(c_, kk_)                                                      \
    bv0 = *(const bf16x8*)&ldsB[c_][kk_][offB[0]];                            \
    bv1 = *(const bf16x8*)&ldsB[c_][kk_][offB[1]];                            \
    bv2 = *(const bf16x8*)&ldsB[c_][kk_][offB[2]];                            \
    bv3 = *(const bf16x8*)&ldsB[c_][kk_][offB[3]];

#define READ_AV(c_, kk_, mh_)                                                 \
    av0 = *(const bf16x8*)&ldsA[c_][kk_][offA[(mh_) * 4 + 0]];                \
    av1 = *(const bf16x8*)&ldsA[c_][kk_][offA[(mh_) * 4 + 1]];                \
    av2 = *(const bf16x8*)&ldsA[c_][kk_][offA[(mh_) * 4 + 2]];                \
    av3 = *(const bf16x8*)&ldsA[c_][kk_][offA[(mh_) * 4 + 3]];

#define MFROW(mi_, av_)                                                       \
    acc[mi_][0] = __builtin_amdgcn_mfma_f32_16x16x32_bf16(av_, bv0, acc[mi_][0], 0, 0, 0); \
    acc[mi_][1] = __builtin_amdgcn_mfma_f32_16x16x32_bf16(av_, bv1, acc[mi_][1], 0, 0, 0); \
    acc[mi_][2] = __builtin_amdgcn_mfma_f32_16x16x32_bf16(av_, bv2, acc[mi_][2], 0, 0, 0); \
    acc[mi_][3] = __builtin_amdgcn_mfma_f32_16x16x32_bf16(av_, bv3, acc[mi_][3], 0, 0, 0);

#define MFMA16(mh_)                                                           \
    __builtin_amdgcn_s_setprio(1);                                            \
    MFROW((mh_) * 4 + 0, av0);                                                \
    MFROW((mh_) * 4 + 1, av1);                                                \
    MFROW((mh_) * 4 + 2, av2);                                                \
    MFROW((mh_) * 4 + 3, av3);                                                \
    __builtin_amdgcn_s_setprio(0);

#define BAR() __builtin_amdgcn_s_barrier()

    const int NT = K >> 6;   // K-tiles of 64; NT=64 here

    // ---- prologue: tile0 full (8 loads) + B(1,0),A(1,0) (4 loads);
    // vmcnt(4) retires tile0, leaves the tile1-kh0 pair in flight.
    STAGE_A(0, 0); STAGE_B(0, 0); STAGE_A(0, 1); STAGE_B(0, 1);
    STAGE_B(1, 0); STAGE_A(1, 0);
    asm volatile("s_waitcnt vmcnt(4)" ::: "memory");
    BAR();

    bf16x8 av0, av1, av2, av3, bv0, bv1, bv2, bv3;

    // ---- main loop ----
    // Stage targets are >=2 phases from their last read (race-free with one
    // barrier/phase); vmcnt(4) at P4 retires exactly through A(T+1,kh1) so
    // tile T+1 is fully resident (and barrier-visible) entering T+1.
#pragma unroll 2
    for (int T = 0; T <= NT - 3; ++T) {
        const int c = T & 1;
        // P1: m0-3 x kk0 ; stage B(T+1,kh1)
        READ_BV(c, 0);
        READ_AV(c, 0, 0);
        STAGE_B(T + 1, 1);
        BAR();
        MFMA16(0);
        // P2: m4-7 x kk0 (bv reused) ; stage A(T+1,kh1)
        READ_AV(c, 0, 1);
        STAGE_A(T + 1, 1);
        BAR();
        MFMA16(1);
        // P3: m0-3 x kk1 ; stage B(T+2,kh0) (last read @P1, 2 phases ago)
        READ_BV(c, 1);
        READ_AV(c, 1, 0);
        STAGE_B(T + 2, 0);
        BAR();
        MFMA16(0);
        // P4: m4-7 x kk1 ; stage A(T+2,kh0) (last read @P2, 2 phases ago)
        READ_AV(c, 1, 1);
        STAGE_A(T + 2, 0);
        asm volatile("s_waitcnt vmcnt(4)" ::: "memory");   // tile T+1 resident
        BAR();
        MFMA16(1);
    }

    // ---- epilogue: tile NT-2 (stage tile NT-1's kh1 units, then drain) ----
    {
        const int c2 = (NT - 2) & 1;
        READ_BV(c2, 0);
        READ_AV(c2, 0, 0);
        STAGE_B(NT - 1, 1);
        BAR();
        MFMA16(0);
        READ_AV(c2, 0, 1);
        STAGE_A(NT - 1, 1);
        BAR();
        MFMA16(1);
        READ_BV(c2, 1);
        READ_AV(c2, 1, 0);
        BAR();
        MFMA16(0);
        READ_AV(c2, 1, 1);
        asm volatile("s_waitcnt vmcnt(0)" ::: "memory");
        BAR();
        MFMA16(1);
    }
    // ---- tile NT-1: all resident & visible, no writers -> no barriers ----
    {
        const int c1 = (NT - 1) & 1;
        READ_BV(c1, 0); READ_AV(c1, 0, 0); MFMA16(0);
        READ_AV(c1, 0, 1); MFMA16(1);
        READ_BV(c1, 1); READ_AV(c1, 1, 0); MFMA16(0);
        READ_AV(c1, 1, 1); MFMA16(1);
    }

#undef STAGE_A
#undef STAGE_B
#undef READ_BV
#undef READ_AV
#undef MFROW
#undef MFMA16
#undef BAR

    // ---- C write: layout col=lane&15, row=quad*4+reg [m89-verified] ----
    const int colBase = blockN0 + wn * 64;
    const int rowBase = blockM0 + wm * 128;
    float biasf[4];
#pragma unroll
    for (int n = 0; n < 4; ++n)
        biasf[n] = bias[colBase + n * 16 + row16];

#pragma unroll
    for (int m = 0; m < 8; ++m) {
        const int row0 = rowBase + m * 16 + quad * 4;
#pragma unroll
        for (int n = 0; n < 4; ++n) {
            const int col = colBase + n * 16 + row16;
#pragma unroll
            for (int r = 0; r < 4; ++r) {
                C[(long long)(row0 + r) * N + col] = acc[m][n][r] + biasf[n];
            }
        }
    }
}

// ---------------- legacy 128x128 GEMM (fallback for odd shapes) -------------
__global__ __launch_bounds__(256, 2) void gemm_bf16_nt(
    const unsigned short* __restrict__ A,
    const unsigned short* __restrict__ Bw,
    const float* __restrict__ bias,
    float*       __restrict__ C,
    int M, int N, int K)
{
    __shared__ unsigned short ldsA[BM * BK];
    __shared__ unsigned short ldsB[BN * BK];

    const int tid   = threadIdx.x;
    const int lane  = tid & 63;
    const int wave  = tid >> 6;
    const int waveM = wave >> 1;
    const int waveN = wave & 1;

    const int blockN0 = blockIdx.x * BN;
    const int blockM0 = blockIdx.y * BM;

    const long long aBase = (long long)blockM0 * K;
    const long long bBase = (long long)blockN0 * K;

    const int rowInChunk = lane >> 3;
    const int colChunkSw = (lane & 7) ^ rowInChunk;
    const int col8       = colChunkSw * 8;

    f32x4 acc[4][4];
#pragma unroll
    for (int i = 0; i < 4; ++i)
#pragma unroll
        for (int j = 0; j < 4; ++j)
            acc[i][j] = (f32x4){0.f, 0.f, 0.f, 0.f};

    const int row16 = lane & 15;
    const int quad  = lane >> 4;
    const int sw    = row16 & 7;

    for (int k0 = 0; k0 < K; k0 += BK) {
        __syncthreads();
#pragma unroll
        for (int c = 0; c < 4; ++c) {
            const int chunk = (wave << 2) | c;
            const int row   = (chunk << 3) | rowInChunk;
            const unsigned short* gA = A  + aBase + (long long)row * K + k0 + col8;
            const unsigned short* gB = Bw + bBase + (long long)row * K + k0 + col8;
            __builtin_amdgcn_global_load_lds(
                (const __attribute__((address_space(1))) unsigned int*)gA,
                (__attribute__((address_space(3))) unsigned int*)&ldsA[chunk * 512],
                16, 0, 0);
            __builtin_amdgcn_global_load_lds(
                (const __attribute__((address_space(1))) unsigned int*)gB,
                (__attribute__((address_space(3))) unsigned int*)&ldsB[chunk * 512],
                16, 0, 0);
        }
        __syncthreads();

#pragma unroll
        for (int kk = 0; kk < 2; ++kk) {
            bf16x8 av[4], bv[4];
#pragma unroll
            for (int i = 0; i < 4; ++i) {
                const int r    = waveM * 64 + i * 16 + row16;
                const int slot = (kk * 4 + quad) ^ sw;
                av[i] = *(const bf16x8*)&ldsA[r * BK + slot * 8];
            }
#pragma unroll
            for (int j = 0; j < 4; ++j) {
                const int r    = waveN * 64 + j * 16 + row16;
                const int slot = (kk * 4 + quad) ^ sw;
                bv[j] = *(const bf16x8*)&ldsB[r * BK + slot * 8];
            }
#pragma unroll
            for (int i = 0; i < 4; ++i)
#pragma unroll
                for (int j = 0; j < 4; ++j)
                    acc[i][j] = __builtin_amdgcn_mfma_f32_16x16x32_bf16(
                        av[i], bv[j], acc[i][j], 0, 0, 0);
        }
    }

    const int colBase = blockN0 + waveN * 64;
    const int rowBase = blockM0 + waveM * 64;
    float biasf[4];
#pragma unroll
    for (int j = 0; j < 4; ++j)
        biasf[j] = bias[colBase + j * 16 + row16];

#pragma unroll
    for (int i = 0; i < 4; ++i) {
        const int row0 = rowBase + i * 16 + quad * 4;
#pragma unroll
        for (int j = 0; j < 4; ++j) {
            const int col = colBase + j * 16 + row16;
#pragma unroll
            for (int r = 0; r < 4; ++r) {
                C[(long long)(row0 + r) * N + col] = acc[i][j][r] + biasf[j];
            }
        }
    }
}

// ---------------- fallback: fused kernel (no workspace) ---------------------
__global__ __launch_bounds__(256) void hqq_gemm_fused_f32(
    const float* __restrict__ A,
    const int*   __restrict__ Wq,
    const float* __restrict__ scale,
    const float* __restrict__ zero,
    const float* __restrict__ bias,
    float*       __restrict__ C,
    int M, int N, int K, int G, int GROUP)
{
    __shared__ unsigned short ldsA[BM * BK];
    __shared__ unsigned short ldsB[BN * BK];

    const int tid   = threadIdx.x;
    const int lane  = tid & 63;
    const int wave  = tid >> 6;
    const int waveM = wave >> 1;
    const int waveN = wave & 1;

    const int blockN0 = blockIdx.x * BN;
    const int blockM0 = blockIdx.y * BM;

    const int row16 = lane & 15;
    const int quad  = lane >> 4;

    f32x4 acc[4][4];
#pragma unroll
    for (int i = 0; i < 4; ++i)
#pragma unroll
        for (int j = 0; j < 4; ++j)
            acc[i][j] = (f32x4){0.f, 0.f, 0.f, 0.f};

    for (int k0 = 0; k0 < K; k0 += BK) {
        const int g = k0 / GROUP;
        int4 ra[4], rb[4];
#pragma unroll
        for (int c = 0; c < 4; ++c) {
            const int chunk = c * 256 + tid;
            const int row   = chunk >> 3;
            const int col   = (chunk & 7) * 8;

            const float* ap = A + (long long)(blockM0 + row) * K + k0 + col;
            const float4 a0 = *(const float4*)(ap);
            const float4 a1 = *(const float4*)(ap + 4);
            int4 da;
            da.x = pack_bf16x2(a0.x, a0.y);
            da.y = pack_bf16x2(a0.z, a0.w);
            da.z = pack_bf16x2(a1.x, a1.y);
            da.w = pack_bf16x2(a1.z, a1.w);
            ra[c] = da;

            const int n = blockN0 + row;
            const float s  = scale[(long long)n * G + g];
            const float z  = zero [(long long)n * G + g];
            const float mz = -z * s;
            const long long wb = (long long)n * K + k0 + col;
            const int4 q0 = *(const int4*)(Wq + wb);
            const int4 q1 = *(const int4*)(Wq + wb + 4);
            int4 db;
            db.x = pack_bf16x2((float)q0.x * s + mz, (float)q0.y * s + mz);
            db.y = pack_bf16x2((float)q0.z * s + mz, (float)q0.w * s + mz);
            db.z = pack_bf16x2((float)q1.x * s + mz, (float)q1.y * s + mz);
            db.w = pack_bf16x2((float)q1.z * s + mz, (float)q1.w * s + mz);
            rb[c] = db;
        }

        __syncthreads();
#pragma unroll
        for (int c = 0; c < 4; ++c) {
            const int chunk = c * 256 + tid;
            *(int4*)&ldsA[chunk * 8] = ra[c];
            *(int4*)&ldsB[chunk * 8] = rb[c];
        }
        __syncthreads();

#pragma unroll
        for (int kk = 0; kk < 2; ++kk) {
            const int kOff = kk * 32 + quad * 8;
            bf16x8 av[4], bv[4];
#pragma unroll
            for (int i = 0; i < 4; ++i)
                av[i] = *(const bf16x8*)&ldsA[(waveM * 64 + i * 16 + row16) * BK + kOff];
#pragma unroll
            for (int j = 0; j < 4; ++j)
                bv[j] = *(const bf16x8*)&ldsB[(waveN * 64 + j * 16 + row16) * BK + kOff];
#pragma unroll
            for (int i = 0; i < 4; ++i)
#pragma unroll
                for (int j = 0; j < 4; ++j)
                    acc[i][j] = __builtin_amdgcn_mfma_f32_16x16x32_bf16(
                        av[i], bv[j], acc[i][j], 0, 0, 0);
        }
    }

    const int colBase = blockN0 + waveN * 64;
    const int rowBase = blockM0 + waveM * 64;
    float biasf[4];
#pragma unroll
    for (int j = 0; j < 4; ++j)
        biasf[j] = bias[colBase + j * 16 + row16];

#pragma unroll
    for (int i = 0; i < 4; ++i) {
        const int row0 = rowBase + i * 16 + quad * 4;
#pragma unroll
        for (int j = 0; j < 4; ++j) {
            const int col = colBase + j * 16 + row16;
#pragma unroll
            for (int r = 0; r < 4; ++r) {
                C[(long long)(row0 + r) * N + col] = acc[i][j][r] + biasf[j];
            }
        }
    }
}

extern "C" void kernel_launch(void* const* d_in, const int* in_sizes, int n_in,
                              void* d_out, int out_size, void* d_ws, size_t ws_size,
                              hipStream_t stream) {
    (void)n_in; (void)out_size;

    const float* x     = (const float*)d_in[0];
    const int*   Wq    = (const int*)d_in[1];
    const float* scale = (const float*)d_in[2];
    const float* zero  = (const float*)d_in[3];
    const float* bias  = (const float*)d_in[4];
    float*       out   = (float*)d_out;

    const int N     = in_sizes[4];            // 4096
    const int G     = in_sizes[2] / N;        // 32
    const int K     = in_sizes[1] / N;        // 4096
    const int M     = in_sizes[0] / K;        // 4096 (B*S)
    const int GROUP = K / G;                  // 128

    const size_t needWs = (size_t)N * K * 2 + (size_t)M * K * 2;  // 64 MB

    const int unitsPerRow = K / 8;            // 512
    const int unitsPerGrp = GROUP / 8;        // 16
    const bool pow2ok =
        (unitsPerRow > 0) && ((unitsPerRow & (unitsPerRow - 1)) == 0) &&
        (unitsPerGrp > 0) && ((unitsPerGrp & (unitsPerGrp - 1)) == 0) &&
        (K % 8 == 0) && (GROUP % 8 == 0);

    if (ws_size >= needWs && pow2ok) {
        unsigned short* Wd = (unsigned short*)d_ws;                        // [N,K] bf16
        unsigned short* Ad = (unsigned short*)((char*)d_ws + (size_t)N * K * 2);  // [M,K] bf16

        const int aUnits = (int)((long long)M * K / 8);
        const int wUnits = (int)((long long)N * K / 8);
        const int rowShift = __builtin_ctz((unsigned)unitsPerRow);
        const int grpShift = __builtin_ctz((unsigned)unitsPerGrp);
        prepass_kernel<<<2048, 256, 0, stream>>>(x, Ad, Wq, scale, zero, Wd,
                                                 aUnits, wUnits, G,
                                                 rowShift, grpShift);

        const int nwg = (N >> 8) * (M >> 8);
        const int NT  = K >> 6;
        if ((M % 256) == 0 && (N % 256) == 0 && (K % 64) == 0 && NT >= 4 &&
            (nwg % 8) == 0) {
            gemm256_8ph<<<nwg, 512, 0, stream>>>(Ad, Wd, bias, out, M, N, K);
        } else {
            dim3 grid(N / BN, M / BM);
            gemm_bf16_nt<<<grid, 256, 0, stream>>>(Ad, Wd, bias, out, M, N, K);
        }
    } else {
        dim3 grid(N / BN, M / BM);
        hqq_gemm_fused_f32<<<grid, 256, 0, stream>>>(x, Wq, scale, zero, bias, out,
                                                     M, N, K, G, GROUP);
    }
}